// Round 7
// baseline (183.698 us; speedup 1.0000x reference)
//
#include <hip/hip_runtime.h>
#include <hip/hip_bf16.h>
#include <math.h>

#define BB   4
#define NN   2048
#define INPT 448

typedef float f32x4 __attribute__((ext_vector_type(4)));
typedef short s16x8 __attribute__((ext_vector_type(8)));
typedef unsigned int u32;

#define MFMA(a,b,c) __builtin_amdgcn_mfma_f32_16x16x32_bf16((a),(b),(c),0,0,0)

// Fragment-layout persistent buffers (fully rewritten every launch)
__device__ __align__(16) unsigned short g_WcatF[4*8*64*8];       // (kg,jf,l) A-frag words
__device__ __align__(16) unsigned short g_WembF[8*8*64*8];       // (kg,cf,l) B-frag words
__device__ __align__(16) unsigned short g_UtF[BB*2*64*4*64*8];   // (b,dir,kk,nf,l) B-frag words, 2MB
__device__ __align__(16) float          g_G2[BB*NN*128];         // fp32 dyn*gate

// ---- fp32 -> bf16 (RNE) helpers ----
__device__ __forceinline__ u32 bf16pk(float a, float b) {
    u32 ua = __builtin_bit_cast(u32, a);
    u32 ub = __builtin_bit_cast(u32, b);
    ua += 0x7fffu + ((ua >> 16) & 1u);
    ub += 0x7fffu + ((ub >> 16) & 1u);
    return (ua >> 16) | (ub & 0xffff0000u);
}
__device__ __forceinline__ unsigned short bf16b(float a) {
    u32 ua = __builtin_bit_cast(u32, a);
    ua += 0x7fffu + ((ua >> 16) & 1u);
    return (unsigned short)(ua >> 16);
}

// ---- k0: pack weights into MFMA fragment layout ----
__global__ void k_weights(const float* __restrict__ Wf, const float* __restrict__ Wb,
                          const float* __restrict__ We) {
    int t = blockIdx.x * 256 + threadIdx.x;
    if (t < 2048) {                          // WcatF word t = (kg*8 + jf)*64 + l
        int l = t & 63, jf = (t >> 6) & 7, kg = t >> 9;
        int j  = jf * 16 + (l & 15);
        int f0 = kg * 32 + (l >> 4) * 8;
        union { u32 u[4]; s16x8 s; } r;
        #pragma unroll
        for (int e = 0; e < 8; e += 2) {
            float v0 = (j < 64) ? Wf[(f0 + e    ) * 64 + j] : Wb[(f0 + e    ) * 64 + (j - 64)];
            float v1 = (j < 64) ? Wf[(f0 + e + 1) * 64 + j] : Wb[(f0 + e + 1) * 64 + (j - 64)];
            r.u[e >> 1] = bf16pk(v0, v1);
        }
        *(s16x8*)&g_WcatF[t * 8] = r.s;
    } else if (t < 2048 + 4096) {            // WembF word idx = (kg*8 + cf)*64 + l
        int idx = t - 2048;
        int l = idx & 63, cf = (idx >> 6) & 7, kg = idx >> 9;
        int c  = cf * 16 + (l & 15);
        int k0 = kg * 32 + (l >> 4) * 8;
        union { u32 u[4]; s16x8 s; } r;
        #pragma unroll
        for (int e = 0; e < 8; e += 2)
            r.u[e >> 1] = bf16pk(We[(k0 + e) * 128 + c], We[(k0 + e + 1) * 128 + c]);
        *(s16x8*)&g_WembF[idx * 8] = r.s;
    }
}

// ---- k1: bid<256 -> UtF (frag layout); bid>=256 -> G2 ----
__global__ __launch_bounds__(256) void k_prep(const float* __restrict__ nfeat,
                                              const float* __restrict__ bemb) {
    __shared__ __align__(16) char sm[24576];
    int tid = threadIdx.x;
    int w = tid >> 6, l = tid & 63, lr = l & 15, lc = l >> 4;
    int bid = blockIdx.x;

    if (bid < 256) {
        int b = bid >> 6, nb = bid & 63;
        unsigned short* ss = (unsigned short*)sm;            // [32 n][128 f] bf16, XOR-swz
        unsigned short* ob = (unsigned short*)(sm + 8192);   // [128 j][32 n] bf16
        const float* base = nfeat + (size_t)(b * NN + nb * 32) * INPT;
        #pragma unroll
        for (int i = 0; i < 4; ++i) {                        // coalesced struct stage
            int node = w * 8 + i * 2 + (l >> 5);
            int c4 = (l & 31) * 4;
            float4 v = *(const float4*)(base + (size_t)node * INPT + 64 + c4);
            int off = node * 256 + c4 * 2; off ^= (node & 7) << 4;
            uint2 pk; pk.x = bf16pk(v.x, v.y); pk.y = bf16pk(v.z, v.w);
            *(uint2*)((char*)ss + off) = pk;
        }
        __syncthreads();
        f32x4 acc[2][2] = {};
        #pragma unroll
        for (int kg = 0; kg < 4; ++kg) {
            s16x8 a0 = *(const s16x8*)&g_WcatF[((kg * 8 + w * 2 + 0) * 64 + l) * 8];
            s16x8 a1 = *(const s16x8*)&g_WcatF[((kg * 8 + w * 2 + 1) * 64 + l) * 8];
            #pragma unroll
            for (int na = 0; na < 2; ++na) {
                int off = (na * 16 + lr) * 256 + kg * 64 + lc * 16; off ^= (lr & 7) << 4;
                s16x8 bf = *(const s16x8*)((char*)ss + off);
                acc[0][na] = MFMA(a0, bf, acc[0][na]);
                acc[1][na] = MFMA(a1, bf, acc[1][na]);
            }
        }
        #pragma unroll
        for (int ja = 0; ja < 2; ++ja)
            #pragma unroll
            for (int na = 0; na < 2; ++na)
                #pragma unroll
                for (int r = 0; r < 4; ++r) {
                    int j = w * 32 + ja * 16 + lc * 4 + r;
                    int n = na * 16 + lr;
                    ob[j * 32 + n] = bf16b(acc[ja][na][r]);
                }
        __syncthreads();
        #pragma unroll
        for (int q = 0; q < 2; ++q) {                        // frag-order write, coalesced
            int idx = q * 256 + tid;
            int dirx = idx >> 8, nf = (idx >> 6) & 3, ll = idx & 63;
            int j = dirx * 64 + nf * 16 + (ll & 15);
            int n0 = (ll >> 4) * 8;
            s16x8 v = *(const s16x8*)&ob[j * 32 + n0];
            *(s16x8*)&g_UtF[((((size_t)(b * 2 + dirx) * 64 + nb) * 4 + nf) * 64 + ll) * 8] = v;
        }
    } else {
        int bid2 = bid - 256;
        int b = bid2 >> 6, mb = bid2 & 63;
        unsigned short* ss = (unsigned short*)sm;            // [32 m][256 k] bf16, XOR-swz
        float* dyls = (float*)(sm + 16384);                  // [32 m][64] f32
        const float* base = nfeat + (size_t)(b * NN + mb * 32) * INPT;
        #pragma unroll
        for (int i = 0; i < 8; ++i) {                        // coalesced stat stage
            int row = w * 8 + i;
            float4 v = *(const float4*)(base + (size_t)row * INPT + 192 + l * 4);
            int off = row * 512 + l * 8; off ^= (row & 7) << 4;
            uint2 pk; pk.x = bf16pk(v.x, v.y); pk.y = bf16pk(v.z, v.w);
            *(uint2*)((char*)ss + off) = pk;
        }
        #pragma unroll
        for (int i = 0; i < 2; ++i) {                        // dyn stage (fp32)
            int row = w * 8 + i * 4 + lc;
            float4 v = *(const float4*)(base + (size_t)row * INPT + lr * 4);
            *(float4*)&dyls[row * 64 + lr * 4] = v;
        }
        __syncthreads();
        f32x4 acc[2][2] = {};
        #pragma unroll
        for (int kg = 0; kg < 8; ++kg) {
            s16x8 a0, a1;
            {
                int off = lr * 512 + kg * 64 + lc * 16; off ^= (lr & 7) << 4;
                a0 = *(const s16x8*)((char*)ss + off);
                a1 = *(const s16x8*)((char*)ss + off + 8192);
            }
            #pragma unroll
            for (int cfi = 0; cfi < 2; ++cfi) {
                s16x8 bf = *(const s16x8*)&g_WembF[((kg * 8 + w * 2 + cfi) * 64 + l) * 8];
                acc[cfi][0] = MFMA(a0, bf, acc[cfi][0]);
                acc[cfi][1] = MFMA(a1, bf, acc[cfi][1]);
            }
        }
        #pragma unroll
        for (int cfi = 0; cfi < 2; ++cfi) {
            int c = (w * 2 + cfi) * 16 + lr;
            float be = bemb[c];
            #pragma unroll
            for (int mf = 0; mf < 2; ++mf)
                #pragma unroll
                for (int r = 0; r < 4; ++r) {
                    int m = mf * 16 + lc * 4 + r;
                    float v = acc[cfi][mf][r] + be;
                    float g = 1.0f / (1.0f + expf(-v));
                    g_G2[(size_t)(b * NN + mb * 32 + m) * 128 + c] = g * dyls[m * 64 + (c & 63)];
                }
        }
    }
}

// ---- asm load (fire-and-forget; only 3 live staging regs per thread) ----
#define GLOAD(dst, p) \
    asm volatile("global_load_dwordx4 %0, %1, off" : "=v"(dst) : "v"(p) : "memory")

// ---- k2: main GEMM h = adj @ U. 2-phase dbuf staging, M=16 x N=64 x K=2048, no split-K ----
__global__ __launch_bounds__(256) void k_main(const float* __restrict__ adjf,
                                              const float* __restrict__ adjb,
                                              const float* __restrict__ biasf,
                                              const float* __restrict__ biasb,
                                              float* __restrict__ out) {
    // LDS: A bf16 dbuf 2 x 2KB @0; B bf16 dbuf 2 x 8KB @4096
    __shared__ __align__(16) char sm[20480];
    int tid = threadIdx.x;
    int w = tid >> 6, l = tid & 63, lr = l & 15, lc = l >> 4;

    // XCD swizzle: each XCD gets one contiguous (b,dir) panel of 128 tiles
    int hw  = blockIdx.x;                     // 1024 = 8 XCDs x 128
    int bid = (hw & 7) * 128 + (hw >> 3);
    int tile = bid & 127, dir = (bid >> 7) & 1, b = bid >> 8;

    const float* adj  = dir ? adjb : adjf;
    const float* bias = dir ? biasb : biasf;
    int m0 = tile * 16;
    const unsigned short* utF = g_UtF + (size_t)(b * 2 + dir) * 131072;

    // staging assignments (per thread, fixed)
    int arow = tid >> 4;                      // 0..15
    int u8   = tid & 15;                      // 8B unit within A row
    const float* asrc = adj + (size_t)(b * NN + m0 + arow) * NN + u8 * 4;
    int awoff = arow * 128 + ((((u8 >> 1) ^ (arow & 7)) << 4)) + (u8 & 1) * 8;
    const unsigned short* bs0 = utF + (size_t)w * 512 + l * 8;      // k-chunk 0
    const unsigned short* bs1 = bs0 + 2048;                          // k-chunk 1
    int boff0 = (w * 64 + l) * 16;
    int boff1 = ((4 + w) * 64 + l) * 16;

    f32x4 acc = {};

    // ---- prologue: stage step 0 into buf0 ----
    {
        f32x4 a0, bv0, bv1;
        GLOAD(a0, asrc);
        GLOAD(bv0, bs0);
        GLOAD(bv1, bs1);
        asm volatile("s_waitcnt vmcnt(0)" : "+v"(a0), "+v"(bv0), "+v"(bv1) : : "memory");
        uint2 pk; pk.x = bf16pk(a0[0], a0[1]); pk.y = bf16pk(a0[2], a0[3]);
        *(uint2*)(sm + awoff) = pk;
        *(f32x4*)(sm + 4096 + boff0) = bv0;
        *(f32x4*)(sm + 4096 + boff1) = bv1;
    }
    __syncthreads();

    // ---- main loop: 32 K-steps of 64 ----
    for (int t = 0; t < 32; ++t) {
        f32x4 an, bn0, bn1;
        bool pre = (t < 31);
        if (pre) {                            // issue next-step loads (in flight across compute)
            GLOAD(an,  asrc + (t + 1) * 64);
            GLOAD(bn0, bs0 + (t + 1) * 4096);
            GLOAD(bn1, bs1 + (t + 1) * 4096);
        }
        // compute step t from buf[t&1]
        char* Ab = sm + (t & 1) * 2048;
        char* Bb = sm + 4096 + (t & 1) * 8192;
        #pragma unroll
        for (int kk = 0; kk < 2; ++kk) {
            s16x8 af = *(const s16x8*)(Ab + lr * 128 + (((kk * 4 + lc) ^ (lr & 7)) << 4));
            s16x8 bf = *(const s16x8*)(Bb + ((kk * 4 + w) * 64 + l) * 16);
            acc = MFMA(af, bf, acc);
        }
        if (pre) {                            // consume staged data into back buffer
            asm volatile("s_waitcnt vmcnt(0)" : "+v"(an), "+v"(bn0), "+v"(bn1) : : "memory");
            char* Ab2 = sm + ((t + 1) & 1) * 2048;
            char* Bb2 = sm + 4096 + ((t + 1) & 1) * 8192;
            uint2 pk; pk.x = bf16pk(an[0], an[1]); pk.y = bf16pk(an[2], an[3]);
            *(uint2*)(Ab2 + awoff) = pk;
            *(f32x4*)(Bb2 + boff0) = bn0;
            *(f32x4*)(Bb2 + boff1) = bn1;
        }
        __syncthreads();
    }

    // ---- epilogue: direct write, no cross-wave reduction ----
    int col = w * 16 + lr;
    float bv = bias[col];
    #pragma unroll
    for (int r = 0; r < 4; ++r) {
        int mrow = m0 + lc * 4 + r;
        size_t o = (size_t)(b * NN + mrow) * 128 + dir * 64 + col;
        out[o] = (acc[r] + bv) * g_G2[o];
    }
}

extern "C" void kernel_launch(void* const* d_in, const int* in_sizes, int n_in,
                              void* d_out, int out_size, void* d_ws, size_t ws_size,
                              hipStream_t stream) {
    (void)in_sizes; (void)n_in; (void)d_ws; (void)ws_size; (void)out_size;
    const float* nfeat = (const float*)d_in[0];
    const float* adjf  = (const float*)d_in[1];
    const float* adjb  = (const float*)d_in[2];
    const float* Wf    = (const float*)d_in[3];
    const float* bf    = (const float*)d_in[4];
    const float* Wb    = (const float*)d_in[5];
    const float* bb    = (const float*)d_in[6];
    const float* We    = (const float*)d_in[7];
    const float* bemb  = (const float*)d_in[8];
    float* out = (float*)d_out;

    hipLaunchKernelGGL(k_weights, dim3(24),   dim3(256), 0, stream, Wf, Wb, We);
    hipLaunchKernelGGL(k_prep,    dim3(512),  dim3(256), 0, stream, nfeat, bemb);
    hipLaunchKernelGGL(k_main,    dim3(1024), dim3(256), 0, stream, adjf, adjb, bf, bb, out);
}